// Round 6
// baseline (227.501 us; speedup 1.0000x reference)
//
#include <hip/hip_runtime.h>

// APoT (8-bit, m=2) quantizer, eval forward — bit-logic, copy-shaped streaming.
//
// Codebook = {0, ±2^-p, ±(2^-p + 2^-q)}: every level is an fp32 with at most
// TWO mantissa bits set, finest bit 2^-15 absolute. Nearest-level with
// searchsorted/argmin-first tie-break == exact integer logic on the bit
// pattern of |xn| (verified absmax == 0.0, R1-R4). Fast path uses
// q0 = x * (1/alpha) (uniform divisor); |2m - mid| <= 8 lanes (~1e-6 of data,
// incl. all exact ties) redo the true IEEE divide under exec mask, so the
// result stays bit-exact vs numpy.
//
// R5 structure: mirror the 6.29 TB/s m13 float4-copy recipe — ONE float4 per
// thread, 32768 one-shot blocks (block churn supplies memory parallelism;
// fat 16-elem threads measured 3.9 TB/s in R2/R4 with the compiler
// serializing in-flight loads at VGPR_Count=16). PLAIN cached loads: the
// harness restore-copy re-warms x into the 256 MB LLC before every timed
// launch, and R3's counters showed FETCH=65.6 MB (half of x served by LLC) —
// NT loads forfeit that. NT stores only (touch-once out; avoid evicting x).

typedef float vfloat4 __attribute__((ext_vector_type(4)));

__device__ __forceinline__ unsigned apot_pick(unsigned a, unsigned s, int& d) {
    // a = bits of clamped |xn| (<= 0x3F800000). Returns level bits (no sign);
    // d = signed distance of the mantissa from the decision midpoint.
    unsigned q;
    if (a >= 0x38000000u) {               // |xn| >= 2^-15 : ~99.999% of data
        const unsigned e    = a >> 23;          // 112..127
        const unsigned m    = a & 0x7FFFFFu;
        const unsigned base = a - m;            // e<<23
        const unsigned g    = 1u << (135u - e); // finest grid bit (abs 2^-15)
        const unsigned L    = 31u - __clz(m | 1u);
        const unsigned bit  = 1u << L;
        const bool fine = (m < g);
        const unsigned lo  = fine ? base       : (base | bit);
        const unsigned hi  = fine ? (base + g) : (base + (bit << 1));
        const unsigned mid = fine ? g : (bit + (bit << 1));
        d = (int)(m + m) - (int)mid;
        const bool pickLo = (d < 0) | ((d == 0) & (s == 0u));
        q = pickLo ? lo : hi;
    } else {
        // |xn| < 2^-15: neighbors {0, 2^-15}; midpoint 2^-16
        d = (int)a - (int)0x37800000u;
        const bool pickZero = (d < 0) | ((d == 0) & (s == 0u));
        q = pickZero ? 0u : 0x38000000u;
    }
    return q;
}

__device__ __forceinline__ float apot_q1(float xv, float r, float alpha_pos) {
    // fast path: approximate quotient; margin test guarantees same decision
    const float q0 = xv * r;
    float xn = fminf(1.0f, fmaxf(-1.0f, q0));
    unsigned u = __float_as_uint(xn);
    unsigned s = u & 0x80000000u;
    int d;
    unsigned q = apot_pick(u & 0x7FFFFFFFu, s, d);
    if (d < 9 && d > -9) {
        // near a decision boundary: redo with exact IEEE divide (rare)
        const float xe = fminf(1.0f, fmaxf(-1.0f, xv / alpha_pos));
        const unsigned ue = __float_as_uint(xe);
        s = ue & 0x80000000u;
        q = apot_pick(ue & 0x7FFFFFFFu, s, d);
    }
    return __uint_as_float(q | s) * alpha_pos;
}

__global__ __launch_bounds__(256) void apot_quant_kernel(
    const float* __restrict__ x,
    const float* __restrict__ alpha,
    float* __restrict__ out,
    int n)
{
    const float alpha_pos = fabsf(alpha[0]) + 1e-5f;
    const float r = 1.0f / alpha_pos;   // uniform: one divide per thread

    const int base = (int)(blockIdx.x * blockDim.x + threadIdx.x) * 4;

    if (base + 3 < n) {
        const vfloat4 v = *(const vfloat4*)(x + base);   // plain: LLC-served
        vfloat4 o;
        o.x = apot_q1(v.x, r, alpha_pos);
        o.y = apot_q1(v.y, r, alpha_pos);
        o.z = apot_q1(v.z, r, alpha_pos);
        o.w = apot_q1(v.w, r, alpha_pos);
        __builtin_nontemporal_store(o, (vfloat4*)(out + base));
    } else if (base < n) {
        for (int e = 0; e < 4 && base + e < n; ++e)
            out[base + e] = apot_q1(x[base + e], r, alpha_pos);
    }
}

extern "C" void kernel_launch(void* const* d_in, const int* in_sizes, int n_in,
                              void* d_out, int out_size, void* d_ws, size_t ws_size,
                              hipStream_t stream) {
    const float* x     = (const float*)d_in[0];
    const float* alpha = (const float*)d_in[1];
    // d_in[2] (codebook) is implied by the bit logic; not read.
    float* out         = (float*)d_out;

    const int n = in_sizes[0];            // 33,554,432
    const int block = 256;
    const int grid = (n / 4 + block - 1) / block;   // 32768 blocks

    apot_quant_kernel<<<grid, block, 0, stream>>>(x, alpha, out, n);
}